// Round 6
// baseline (295.372 us; speedup 1.0000x reference)
//
#include <hip/hip_runtime.h>
#include <hip/hip_bf16.h>
#include <stdint.h>

// MHA fwd: x[4,2048,1024] fp32, w_qkv[3072,1024], w_o[1024,1024]
// bf16 MFMA pipeline: cast -> QKV gemm (scale folded into q; V stored
// tile-major with 8B XOR swizzle) -> flash attention (S^T trick: P stays in
// registers, K=16 PV MFMAs, conflict-free V reads, double-buffered async K/V
// staging, one barrier/iter, XCD-local grid) -> out gemm

#define B_   4
#define T_   2048
#define H_   16
#define DK_  64
#define C_   1024
#define M_   (B_*T_)    // 8192 rows
#define N1_  (3*C_)     // 3072
#define LOG2E 1.44269504088896340736f
#define SCFOLD (0.125f * LOG2E)   // folded into q at QKV epilogue

using short8  = __attribute__((ext_vector_type(8))) short;
using short4v = __attribute__((ext_vector_type(4))) short;
using f32x4   = __attribute__((ext_vector_type(4))) float;
typedef unsigned short u16;

__device__ __forceinline__ u16 f2bf(float f) {       // RNE (used in epilogues)
  unsigned u = __float_as_uint(f);
  u += 0x7FFF + ((u >> 16) & 1);
  return (u16)(u >> 16);
}
__device__ __forceinline__ u16 f2bf_fast(float f) {  // round-half-up, 2 ops
  return (u16)((__float_as_uint(f) + 0x8000u) >> 16);
}

// async global->LDS, 16B per lane; lds ptr is wave-uniform base, HW adds lane*16
__device__ __forceinline__ void gld_lds16(void* lds, const void* g) {
  __builtin_amdgcn_global_load_lds(
      (__attribute__((address_space(1))) void*)(g),
      (__attribute__((address_space(3))) void*)(lds), 16, 0, 0);
}

// ---------------- fp32 -> bf16 cast (all three tensors, one launch) ----------
__global__ void cast_all(const float* __restrict__ x, const float* __restrict__ wq,
                         const float* __restrict__ wo, u16* __restrict__ xb,
                         u16* __restrict__ wqb, u16* __restrict__ wob) {
  const int nx = M_ * C_ / 4, nq = N1_ * C_ / 4;
  int i = blockIdx.x * blockDim.x + threadIdx.x;
  const float* src; u16* dst; int j;
  if (i < nx)            { src = x;  dst = xb;  j = i; }
  else if (i < nx + nq)  { src = wq; dst = wqb; j = i - nx; }
  else                   { src = wo; dst = wob; j = i - nx - nq; }
  float4 v = ((const float4*)src)[j];
  ushort4 o;
  o.x = f2bf(v.x); o.y = f2bf(v.y); o.z = f2bf(v.z); o.w = f2bf(v.w);
  ((ushort4*)dst)[j] = o;
}

// ---------------- BT GEMM: C[m,n] = sum_k A[m,k]*B[n,k] ----------------
// 128x128 tile, BK=32, 4 waves in 2x2, each wave 64x64 (4x4 MFMA 16x16x32).
// MODE 0: epilogue scatters qkv -> q[B,H,T,64] (pre-scaled by SCFOLD),
//         k[B,H,T,64], and V in flash-ready tile-major swizzled layout:
//         vt[(bh*32+kt)*64 + d]*16 units; unit u=(t>>2)&15 at p = u^(d&15),
//         each unit = 4 keys (ushort4) of one d -> one packed 8B store.
// MODE 1: epilogue writes fp32 C row-major [M,N]
template <int MODE>
__global__ __launch_bounds__(256)
void gemm_bt(const u16* __restrict__ A, const u16* __restrict__ Bm,
             void* __restrict__ out0, void* __restrict__ out1, void* __restrict__ out2,
             int K, int N) {
  __shared__ __attribute__((aligned(16))) u16 As[128 * 32];
  __shared__ __attribute__((aligned(16))) u16 Bs[128 * 32];
  const int tid  = threadIdx.x;
  const int w    = tid >> 6, lane = tid & 63;
  const int quad = lane >> 4, l15 = lane & 15;
  const int wm   = w >> 1, wn = w & 1;
  const int m0   = blockIdx.y * 128, n0 = blockIdx.x * 128;

  f32x4 acc[4][4];
#pragma unroll
  for (int i = 0; i < 4; i++)
#pragma unroll
    for (int j = 0; j < 4; j++) acc[i][j] = f32x4{0.f, 0.f, 0.f, 0.f};

  const int nkt = K >> 5;
  for (int kt = 0; kt < nkt; ++kt) {
    __syncthreads();
    // stage A,B tiles: 128x32 bf16 = 8KB each = 512 chunks of 16B
#pragma unroll
    for (int c = 0; c < 2; ++c) {
      int chunk = c * 256 + tid;
      int row = chunk >> 2, col = (chunk & 3) << 3;
      gld_lds16(As + (c * 256 + w * 64) * 8, A  + (size_t)(m0 + row) * K + kt * 32 + col);
      gld_lds16(Bs + (c * 256 + w * 64) * 8, Bm + (size_t)(n0 + row) * K + kt * 32 + col);
    }
    __syncthreads();
    short8 af[4], bf[4];
#pragma unroll
    for (int i = 0; i < 4; i++)
      af[i] = *(const short8*)(As + (wm * 64 + i * 16 + l15) * 32 + quad * 8);
#pragma unroll
    for (int j = 0; j < 4; j++)
      bf[j] = *(const short8*)(Bs + (wn * 64 + j * 16 + l15) * 32 + quad * 8);
#pragma unroll
    for (int i = 0; i < 4; i++)
#pragma unroll
      for (int j = 0; j < 4; j++)
        acc[i][j] = __builtin_amdgcn_mfma_f32_16x16x32_bf16(af[i], bf[j], acc[i][j], 0, 0, 0);
  }

  // epilogue: C/D layout col=lane&15, row=quad*4+reg  (m89-verified)
  if (MODE == 0) {
    u16* q  = (u16*)out0;
    u16* k  = (u16*)out1;
    u16* vt = (u16*)out2;
#pragma unroll
    for (int i = 0; i < 4; i++) {
      int m = m0 + wm * 64 + i * 16 + quad * 4;   // + r below, never crosses b boundary
      int b = m >> 11, t = m & 2047;              // t multiple of 4
#pragma unroll
      for (int j = 0; j < 4; j++) {
        int f = n0 + wn * 64 + j * 16 + l15;
        int s = f >> 10, h = (f >> 6) & 15, d = f & 63;
        if (s == 2) {
          ushort4 pk;                              // keys t..t+3 of dim d = one unit
          pk.x = f2bf(acc[i][j][0]); pk.y = f2bf(acc[i][j][1]);
          pk.z = f2bf(acc[i][j][2]); pk.w = f2bf(acc[i][j][3]);
          int kt2 = t >> 6;
          int u   = (t >> 2) & 15;
          int pp  = u ^ (d & 15);                  // 8B swizzle for bank-free reads
          *(ushort4*)(vt + ((((size_t)(b * H_ + h) * 32 + kt2) * 64 + d) * 16 + pp) * 4) = pk;
        } else {
          u16* dst = (s == 0) ? q : k;
          float sc = (s == 0) ? SCFOLD : 1.0f;
#pragma unroll
          for (int r = 0; r < 4; r++)
            dst[(((size_t)(b * H_ + h)) * T_ + (t + r)) * DK_ + d] = f2bf(acc[i][j][r] * sc);
        }
      }
    }
  } else {
    float* outp = (float*)out0;
#pragma unroll
    for (int i = 0; i < 4; i++) {
      int m = m0 + wm * 64 + i * 16 + quad * 4;
#pragma unroll
      for (int j = 0; j < 4; j++) {
        int n = n0 + wn * 64 + j * 16 + l15;
#pragma unroll
        for (int r = 0; r < 4; r++)
          outp[(size_t)(m + r) * N + n] = acc[i][j][r];
      }
    }
  }
}

// ---------------- flash attention (S^T / register-P / dbuf) ----------------
// grid (B*H, T/128): flat%8 == bh%8 -> all q-blocks of a head on one XCD.
// 256 thr, wave w owns 32 Q-rows (2 x 16-row tiles). KT=64 keys per iter.
// q (pre-scaled), k: [B,H,T,64]; vt: tile-major swizzled (see gemm_bt MODE 0);
// out ao: [B,T,H*64] bf16
//
// S^T = K·Q^T via 16x16x32 (operand swap). S^T C-layout: lane holds
// q=l15, keys=quad*4+r — exactly the K=16 MFMA A-fragment layout, so
// exp(S^T) packs directly into mfma_f32_16x16x16bf16_1k A-operands for
// O += P·V and rowsum += P·1. P never touches LDS.
// K staged with 16B XOR source swizzle (b128 reads at bank floor).
// V staged as a LINEAR copy (global already swizzled): lane reading logical
// unit u = nj*4+quad of row d finds it at p = u^l15 -> every instruction
// touches all 16 8B-slots, 4 lanes each = 4 words/bank = bank floor.
__global__ __launch_bounds__(256)
void flash_kernel(const u16* __restrict__ Q, const u16* __restrict__ Kg,
                  const u16* __restrict__ Vt, u16* __restrict__ AO) {
  __shared__ __attribute__((aligned(16))) u16 KVs[2][2][64 * 64];  // [buf][K/V]
  const int tid  = threadIdx.x;
  const int w    = tid >> 6, lane = tid & 63;
  const int quad = lane >> 4, l15 = lane & 15;
  const int bh   = blockIdx.x;
  const int q0   = blockIdx.y * 128;
  const u16* Qb = Q  + (size_t)bh * T_ * DK_;
  const u16* Kb = Kg + (size_t)bh * T_ * DK_;
  const u16* Vb = Vt + (size_t)bh * T_ * DK_;   // 32 tiles x 4096 u16, contiguous

  // Q fragments (B-operand of S^T = K·Q^T): lane n=q=l15 holds d=quad*8+j.
  short8 qf[2][2];
#pragma unroll
  for (int mi = 0; mi < 2; mi++)
#pragma unroll
    for (int ks = 0; ks < 2; ks++)
      qf[mi][ks] = *(const short8*)(Qb + (size_t)(q0 + w * 32 + mi * 16 + l15) * DK_ + ks * 32 + quad * 8);

  // ones A/B-fragment (bf16 1.0 x4) for K=16 rowsum MFMA
  short4v ones;
#pragma unroll
  for (int z = 0; z < 4; z++) ones[z] = (short)0x3F80;

  f32x4 O[2][4];       // rows q=quad*4+r, cols d=dj*16+l15 (C/D layout)
  f32x4 rowsum[2];
#pragma unroll
  for (int mi = 0; mi < 2; mi++) {
    rowsum[mi] = f32x4{0.f, 0.f, 0.f, 0.f};
#pragma unroll
    for (int dj = 0; dj < 4; dj++) O[mi][dj] = f32x4{0.f, 0.f, 0.f, 0.f};
  }

  const int swz = l15 & 7;
  const int NT  = T_ / 64;

  // stage tile kt into buffer b (async DMA). K: source-swizzled 16B chunks.
  // V: plain linear copy of the pre-swizzled 8KB tile.
  auto stage = [&](int kt, int b) {
#pragma unroll
    for (int c = 0; c < 2; ++c) {
      int s = c * 256 + tid;
      int row = s >> 3, cc = (s & 7) ^ (row & 7);
      gld_lds16(&KVs[b][0][(c * 256 + w * 64) * 8], Kb + (size_t)kt * 4096 + row * 64 + cc * 8);
      gld_lds16(&KVs[b][1][(c * 256 + w * 64) * 8], Vb + (size_t)kt * 4096 + s * 8);
    }
  };

  stage(0, 0);   // prologue

  for (int kt = 0; kt < NT; ++kt) {
    __syncthreads();               // drains this wave's DMA for buf[kt&1]
    if (kt + 1 < NT) stage(kt + 1, (kt + 1) & 1);   // hidden by compute below
    const u16* Ks = KVs[kt & 1][0];
    const u16* Vs = KVs[kt & 1][1];

    // S^T = K·Q^T: A=K-frag (lane m=key=l15, k=d chunks), B=qf.
    f32x4 st[2][4];
#pragma unroll
    for (int mi = 0; mi < 2; mi++)
#pragma unroll
      for (int nj = 0; nj < 4; nj++) st[mi][nj] = f32x4{0.f, 0.f, 0.f, 0.f};
#pragma unroll
    for (int ks = 0; ks < 2; ks++) {
#pragma unroll
      for (int nj = 0; nj < 4; nj++) {
        short8 kfr = *(const short8*)(Ks + (nj * 16 + l15) * 64 + (((ks * 4 + quad) ^ swz) * 8));
        st[0][nj] = __builtin_amdgcn_mfma_f32_16x16x32_bf16(kfr, qf[0][ks], st[0][nj], 0, 0, 0);
        st[1][nj] = __builtin_amdgcn_mfma_f32_16x16x32_bf16(kfr, qf[1][ks], st[1][nj], 0, 0, 0);
      }
    }

    // exp in-place -> P fragments (K=16 A-operand layout, registers only)
    short4v pf[2][4];
#pragma unroll
    for (int mi = 0; mi < 2; mi++)
#pragma unroll
      for (int nj = 0; nj < 4; nj++)
#pragma unroll
        for (int r = 0; r < 4; r++)
          pf[mi][nj][r] = (short)f2bf_fast(__builtin_amdgcn_exp2f(st[mi][nj][r]));

    // O += P·V ; rowsum += P·1   (V unit u=nj*4+quad at physical p=u^l15)
#pragma unroll
    for (int nj = 0; nj < 4; nj++) {
      rowsum[0] = __builtin_amdgcn_mfma_f32_16x16x16bf16_1k(pf[0][nj], ones, rowsum[0], 0, 0, 0);
      rowsum[1] = __builtin_amdgcn_mfma_f32_16x16x16bf16_1k(pf[1][nj], ones, rowsum[1], 0, 0, 0);
#pragma unroll
      for (int dj = 0; dj < 4; dj++) {
        int p = (nj * 4 + quad) ^ l15;
        short4v vfr = *(const short4v*)(Vs + (dj * 16 + l15) * 64 + p * 4);
        O[0][dj] = __builtin_amdgcn_mfma_f32_16x16x16bf16_1k(pf[0][nj], vfr, O[0][dj], 0, 0, 0);
        O[1][dj] = __builtin_amdgcn_mfma_f32_16x16x16bf16_1k(pf[1][nj], vfr, O[1][dj], 0, 0, 0);
      }
    }
  }

  // epilogue: rowsum[mi][r] holds the full key-sum for q-row quad*4+r
  const int b = bh >> 4, h = bh & 15;
#pragma unroll
  for (int mi = 0; mi < 2; mi++) {
#pragma unroll
    for (int r = 0; r < 4; r++) {
      float inv = 1.0f / rowsum[mi][r];
      int t = q0 + w * 32 + mi * 16 + quad * 4 + r;
#pragma unroll
      for (int dj = 0; dj < 4; dj++)
        AO[((size_t)(b * T_ + t)) * C_ + h * DK_ + dj * 16 + l15] = f2bf(O[mi][dj][r] * inv);
    }
  }
}

extern "C" void kernel_launch(void* const* d_in, const int* in_sizes, int n_in,
                              void* d_out, int out_size, void* d_ws, size_t ws_size,
                              hipStream_t stream) {
  const float* x    = (const float*)d_in[0];
  const float* wqkv = (const float*)d_in[1];
  const float* wo   = (const float*)d_in[2];

  char* p = (char*)d_ws;
  u16* xb    = (u16*)p; p += (size_t)M_ * C_ * 2;     // 16.8 MB
  u16* wqkvb = (u16*)p; p += (size_t)N1_ * C_ * 2;    //  6.3 MB
  u16* wob   = (u16*)p; p += (size_t)C_ * C_ * 2;     //  2.1 MB
  u16* qb    = (u16*)p; p += (size_t)M_ * C_ * 2;     // 16.8 MB  [B,H,T,64]
  u16* kb    = (u16*)p; p += (size_t)M_ * C_ * 2;     // 16.8 MB  [B,H,T,64]
  u16* vtb   = (u16*)p; p += (size_t)M_ * C_ * 2;     // 16.8 MB  tile-major swizzled
  u16* aob   = (u16*)p; p += (size_t)M_ * C_ * 2;     // 16.8 MB  [B,T,C]

  const int ncast = (M_ * C_ + N1_ * C_ + C_ * C_) / 4;
  cast_all<<<(ncast + 255) / 256, 256, 0, stream>>>(x, wqkv, wo, xb, wqkvb, wob);

  gemm_bt<0><<<dim3(N1_ / 128, M_ / 128), 256, 0, stream>>>(xb, wqkvb, qb, kb, vtb, C_, N1_);

  // grid (bh, qb): flat%8 == bh%8 -> all q-blocks of a head on one XCD
  flash_kernel<<<dim3(B_ * H_, T_ / 128), 256, 0, stream>>>(qb, kb, vtb, aob);

  gemm_bt<1><<<dim3(C_ / 128, M_ / 128), 256, 0, stream>>>(aob, wob, d_out, nullptr, nullptr, C_, C_);
}

// Round 7
// 286.884 us; speedup vs baseline: 1.0296x; 1.0296x over previous
//
#include <hip/hip_runtime.h>
#include <hip/hip_bf16.h>
#include <stdint.h>

// MHA fwd: x[4,2048,1024] fp32, w_qkv[3072,1024], w_o[1024,1024]
// bf16 MFMA pipeline: cast -> QKV gemm (scale folded into q; V stored
// tile-major with 8B XOR swizzle) -> flash attention (S^T trick: P stays in
// registers, K=16 PV MFMAs, per-nj interleaved pipeline to break pipe
// convoying, double-buffered async K/V staging, XCD-local grid) -> out gemm

#define B_   4
#define T_   2048
#define H_   16
#define DK_  64
#define C_   1024
#define M_   (B_*T_)    // 8192 rows
#define N1_  (3*C_)     // 3072
#define LOG2E 1.44269504088896340736f
#define SCFOLD (0.125f * LOG2E)   // folded into q at QKV epilogue

using short8  = __attribute__((ext_vector_type(8))) short;
using short4v = __attribute__((ext_vector_type(4))) short;
using f32x4   = __attribute__((ext_vector_type(4))) float;
typedef unsigned short u16;

__device__ __forceinline__ u16 f2bf(float f) {       // RNE (used in epilogues)
  unsigned u = __float_as_uint(f);
  u += 0x7FFF + ((u >> 16) & 1);
  return (u16)(u >> 16);
}

// exp2 + bf16-convert + pack 4 floats -> short4v: 4 exp, 4 add, 2 perm
__device__ __forceinline__ short4v packexp(f32x4 s) {
  unsigned u0 = __float_as_uint(__builtin_amdgcn_exp2f(s[0])) + 0x8000u;
  unsigned u1 = __float_as_uint(__builtin_amdgcn_exp2f(s[1])) + 0x8000u;
  unsigned u2 = __float_as_uint(__builtin_amdgcn_exp2f(s[2])) + 0x8000u;
  unsigned u3 = __float_as_uint(__builtin_amdgcn_exp2f(s[3])) + 0x8000u;
  union { unsigned w[2]; short4v s4; } cv;
  cv.w[0] = __builtin_amdgcn_perm(u1, u0, 0x07060302);  // {bf(u1),bf(u0)}
  cv.w[1] = __builtin_amdgcn_perm(u3, u2, 0x07060302);  // {bf(u3),bf(u2)}
  return cv.s4;
}

// async global->LDS, 16B per lane; lds ptr is wave-uniform base, HW adds lane*16
__device__ __forceinline__ void gld_lds16(void* lds, const void* g) {
  __builtin_amdgcn_global_load_lds(
      (__attribute__((address_space(1))) void*)(g),
      (__attribute__((address_space(3))) void*)(lds), 16, 0, 0);
}

// ---------------- fp32 -> bf16 cast (all three tensors, one launch) ----------
__global__ void cast_all(const float* __restrict__ x, const float* __restrict__ wq,
                         const float* __restrict__ wo, u16* __restrict__ xb,
                         u16* __restrict__ wqb, u16* __restrict__ wob) {
  const int nx = M_ * C_ / 4, nq = N1_ * C_ / 4;
  int i = blockIdx.x * blockDim.x + threadIdx.x;
  const float* src; u16* dst; int j;
  if (i < nx)            { src = x;  dst = xb;  j = i; }
  else if (i < nx + nq)  { src = wq; dst = wqb; j = i - nx; }
  else                   { src = wo; dst = wob; j = i - nx - nq; }
  float4 v = ((const float4*)src)[j];
  ushort4 o;
  o.x = f2bf(v.x); o.y = f2bf(v.y); o.z = f2bf(v.z); o.w = f2bf(v.w);
  ((ushort4*)dst)[j] = o;
}

// ---------------- BT GEMM: C[m,n] = sum_k A[m,k]*B[n,k] ----------------
// 128x128 tile, BK=32, 4 waves in 2x2, each wave 64x64 (4x4 MFMA 16x16x32).
// MODE 0: epilogue scatters qkv -> q[B,H,T,64] (pre-scaled by SCFOLD),
//         k[B,H,T,64], and V in flash-ready tile-major swizzled layout:
//         per (bh,kt) 64x16-unit tile; unit u=(t>>2)&15 at p = u^(d&15).
// MODE 1: epilogue writes fp32 C row-major [M,N]
template <int MODE>
__global__ __launch_bounds__(256)
void gemm_bt(const u16* __restrict__ A, const u16* __restrict__ Bm,
             void* __restrict__ out0, void* __restrict__ out1, void* __restrict__ out2,
             int K, int N) {
  __shared__ __attribute__((aligned(16))) u16 As[128 * 32];
  __shared__ __attribute__((aligned(16))) u16 Bs[128 * 32];
  const int tid  = threadIdx.x;
  const int w    = tid >> 6, lane = tid & 63;
  const int quad = lane >> 4, l15 = lane & 15;
  const int wm   = w >> 1, wn = w & 1;
  const int m0   = blockIdx.y * 128, n0 = blockIdx.x * 128;

  f32x4 acc[4][4];
#pragma unroll
  for (int i = 0; i < 4; i++)
#pragma unroll
    for (int j = 0; j < 4; j++) acc[i][j] = f32x4{0.f, 0.f, 0.f, 0.f};

  const int nkt = K >> 5;
  for (int kt = 0; kt < nkt; ++kt) {
    __syncthreads();
    // stage A,B tiles: 128x32 bf16 = 8KB each = 512 chunks of 16B
#pragma unroll
    for (int c = 0; c < 2; ++c) {
      int chunk = c * 256 + tid;
      int row = chunk >> 2, col = (chunk & 3) << 3;
      gld_lds16(As + (c * 256 + w * 64) * 8, A  + (size_t)(m0 + row) * K + kt * 32 + col);
      gld_lds16(Bs + (c * 256 + w * 64) * 8, Bm + (size_t)(n0 + row) * K + kt * 32 + col);
    }
    __syncthreads();
    short8 af[4], bf[4];
#pragma unroll
    for (int i = 0; i < 4; i++)
      af[i] = *(const short8*)(As + (wm * 64 + i * 16 + l15) * 32 + quad * 8);
#pragma unroll
    for (int j = 0; j < 4; j++)
      bf[j] = *(const short8*)(Bs + (wn * 64 + j * 16 + l15) * 32 + quad * 8);
#pragma unroll
    for (int i = 0; i < 4; i++)
#pragma unroll
      for (int j = 0; j < 4; j++)
        acc[i][j] = __builtin_amdgcn_mfma_f32_16x16x32_bf16(af[i], bf[j], acc[i][j], 0, 0, 0);
  }

  // epilogue: C/D layout col=lane&15, row=quad*4+reg  (m89-verified)
  if (MODE == 0) {
    u16* q  = (u16*)out0;
    u16* k  = (u16*)out1;
    u16* vt = (u16*)out2;
#pragma unroll
    for (int i = 0; i < 4; i++) {
      int m = m0 + wm * 64 + i * 16 + quad * 4;   // + r below, never crosses b boundary
      int b = m >> 11, t = m & 2047;              // t multiple of 4
#pragma unroll
      for (int j = 0; j < 4; j++) {
        int f = n0 + wn * 64 + j * 16 + l15;
        int s = f >> 10, h = (f >> 6) & 15, d = f & 63;
        if (s == 2) {
          ushort4 pk;                              // keys t..t+3 of dim d = one unit
          pk.x = f2bf(acc[i][j][0]); pk.y = f2bf(acc[i][j][1]);
          pk.z = f2bf(acc[i][j][2]); pk.w = f2bf(acc[i][j][3]);
          int kt2 = t >> 6;
          int u   = (t >> 2) & 15;
          int pp  = u ^ (d & 15);                  // 8B swizzle for bank-free reads
          *(ushort4*)(vt + ((((size_t)(b * H_ + h) * 32 + kt2) * 64 + d) * 16 + pp) * 4) = pk;
        } else {
          u16* dst = (s == 0) ? q : k;
          float sc = (s == 0) ? SCFOLD : 1.0f;
#pragma unroll
          for (int r = 0; r < 4; r++)
            dst[(((size_t)(b * H_ + h)) * T_ + (t + r)) * DK_ + d] = f2bf(acc[i][j][r] * sc);
        }
      }
    }
  } else {
    float* outp = (float*)out0;
#pragma unroll
    for (int i = 0; i < 4; i++) {
      int m = m0 + wm * 64 + i * 16 + quad * 4;
#pragma unroll
      for (int j = 0; j < 4; j++) {
        int n = n0 + wn * 64 + j * 16 + l15;
#pragma unroll
        for (int r = 0; r < 4; r++)
          outp[(size_t)(m + r) * N + n] = acc[i][j][r];
      }
    }
  }
}

// ---------------- flash attention (S^T / register-P / dbuf / interleaved) ----
// grid (B*H, T/128): flat%8 == bh%8 -> all q-blocks of a head on one XCD.
// 256 thr, wave w owns 32 Q-rows (2 x 16-row tiles). KT=64 keys per iter.
//
// S^T = K·Q^T via 16x16x32 (operand swap). S^T C-layout (q=l15, key=quad*4+r)
// IS the K=16 MFMA A-fragment layout -> exp(S^T) packs straight into
// mfma_f32_16x16x16bf16_1k A-operands for O += P·V, rowsum += P·1.
// K-loop is organized as 4 per-nj units each mixing QK-MFMA / exp(trans) /
// pack(VALU) / PV-MFMA / ds_reads so lockstepped waves don't convoy on one
// pipe. K staged with 16B XOR source swizzle; V pre-swizzled in global
// (8B units, p = u^(d&15)) and staged linearly -> both at LDS bank floor.
__global__ __launch_bounds__(256)
void flash_kernel(const u16* __restrict__ Q, const u16* __restrict__ Kg,
                  const u16* __restrict__ Vt, u16* __restrict__ AO) {
  __shared__ __attribute__((aligned(16))) u16 KVs[2][2][64 * 64];  // [buf][K/V]
  const int tid  = threadIdx.x;
  const int w    = tid >> 6, lane = tid & 63;
  const int quad = lane >> 4, l15 = lane & 15;
  const int bh   = blockIdx.x;
  const int q0   = blockIdx.y * 128;
  const u16* Qb = Q  + (size_t)bh * T_ * DK_;
  const u16* Kb = Kg + (size_t)bh * T_ * DK_;
  const u16* Vb = Vt + (size_t)bh * T_ * DK_;   // 32 tiles x 4096 u16, contiguous

  // Q fragments (B-operand of S^T = K·Q^T): lane n=q=l15 holds d=quad*8+j.
  short8 qf[2][2];
#pragma unroll
  for (int mi = 0; mi < 2; mi++)
#pragma unroll
    for (int ks = 0; ks < 2; ks++)
      qf[mi][ks] = *(const short8*)(Qb + (size_t)(q0 + w * 32 + mi * 16 + l15) * DK_ + ks * 32 + quad * 8);

  // ones A/B-fragment (bf16 1.0 x4) for K=16 rowsum MFMA
  short4v ones;
#pragma unroll
  for (int z = 0; z < 4; z++) ones[z] = (short)0x3F80;

  f32x4 O[2][4];       // rows q=quad*4+r, cols d=dj*16+l15 (C/D layout)
  f32x4 rowsum[2];
#pragma unroll
  for (int mi = 0; mi < 2; mi++) {
    rowsum[mi] = f32x4{0.f, 0.f, 0.f, 0.f};
#pragma unroll
    for (int dj = 0; dj < 4; dj++) O[mi][dj] = f32x4{0.f, 0.f, 0.f, 0.f};
  }

  const int swz = l15 & 7;
  const int NT  = T_ / 64;
  // kt-invariant LDS read offsets (elements)
  const int koff0 = ((quad) ^ swz) * 8;            // ks=0 K chunk
  const int koff1 = ((4 + quad) ^ swz) * 8;        // ks=1 K chunk
  int voff[4];
#pragma unroll
  for (int nj = 0; nj < 4; nj++) voff[nj] = ((nj * 4 + quad) ^ l15) * 4;

  // stage tile kt into buffer b (async DMA). K: source-swizzled 16B chunks.
  // V: plain linear copy of the pre-swizzled 8KB tile.
  auto stage = [&](int kt, int b) {
#pragma unroll
    for (int c = 0; c < 2; ++c) {
      int s = c * 256 + tid;
      int row = s >> 3, cc = (s & 7) ^ (row & 7);
      gld_lds16(&KVs[b][0][(c * 256 + w * 64) * 8], Kb + (size_t)kt * 4096 + row * 64 + cc * 8);
      gld_lds16(&KVs[b][1][(c * 256 + w * 64) * 8], Vb + (size_t)kt * 4096 + s * 8);
    }
  };

  stage(0, 0);   // prologue

  for (int kt = 0; kt < NT; ++kt) {
    __syncthreads();               // DMA for buf[kt&1] landed during last iter
    if (kt + 1 < NT) stage(kt + 1, (kt + 1) & 1);   // hidden by compute below
    const u16* Ks = KVs[kt & 1][0];
    const u16* Vs = KVs[kt & 1][1];

    // 4 interleaved units: QK-MFMA -> exp/pack -> rowsum+PV MFMAs (+ds reads)
#pragma unroll
    for (int nj = 0; nj < 4; nj++) {
      const u16* krow = Ks + (nj * 16 + l15) * 64;
      short8 kfr0 = *(const short8*)(krow + koff0);
      short8 kfr1 = *(const short8*)(krow + koff1);
      f32x4 st0 = f32x4{0.f, 0.f, 0.f, 0.f};
      f32x4 st1 = f32x4{0.f, 0.f, 0.f, 0.f};
      st0 = __builtin_amdgcn_mfma_f32_16x16x32_bf16(kfr0, qf[0][0], st0, 0, 0, 0);
      st0 = __builtin_amdgcn_mfma_f32_16x16x32_bf16(kfr1, qf[0][1], st0, 0, 0, 0);
      st1 = __builtin_amdgcn_mfma_f32_16x16x32_bf16(kfr0, qf[1][0], st1, 0, 0, 0);
      st1 = __builtin_amdgcn_mfma_f32_16x16x32_bf16(kfr1, qf[1][1], st1, 0, 0, 0);
      short4v pf0 = packexp(st0);
      short4v pf1 = packexp(st1);
      rowsum[0] = __builtin_amdgcn_mfma_f32_16x16x16bf16_1k(pf0, ones, rowsum[0], 0, 0, 0);
      rowsum[1] = __builtin_amdgcn_mfma_f32_16x16x16bf16_1k(pf1, ones, rowsum[1], 0, 0, 0);
#pragma unroll
      for (int dj = 0; dj < 4; dj++) {
        short4v vfr = *(const short4v*)(Vs + (dj * 16 + l15) * 64 + voff[nj]);
        O[0][dj] = __builtin_amdgcn_mfma_f32_16x16x16bf16_1k(pf0, vfr, O[0][dj], 0, 0, 0);
        O[1][dj] = __builtin_amdgcn_mfma_f32_16x16x16bf16_1k(pf1, vfr, O[1][dj], 0, 0, 0);
      }
    }
  }

  // epilogue: rowsum[mi][r] holds the full key-sum for q-row quad*4+r
  const int b = bh >> 4, h = bh & 15;
#pragma unroll
  for (int mi = 0; mi < 2; mi++) {
#pragma unroll
    for (int r = 0; r < 4; r++) {
      float inv = 1.0f / rowsum[mi][r];
      int t = q0 + w * 32 + mi * 16 + quad * 4 + r;
#pragma unroll
      for (int dj = 0; dj < 4; dj++)
        AO[((size_t)(b * T_ + t)) * C_ + h * DK_ + dj * 16 + l15] = f2bf(O[mi][dj][r] * inv);
    }
  }
}

extern "C" void kernel_launch(void* const* d_in, const int* in_sizes, int n_in,
                              void* d_out, int out_size, void* d_ws, size_t ws_size,
                              hipStream_t stream) {
  const float* x    = (const float*)d_in[0];
  const float* wqkv = (const float*)d_in[1];
  const float* wo   = (const float*)d_in[2];

  char* p = (char*)d_ws;
  u16* xb    = (u16*)p; p += (size_t)M_ * C_ * 2;     // 16.8 MB
  u16* wqkvb = (u16*)p; p += (size_t)N1_ * C_ * 2;    //  6.3 MB
  u16* wob   = (u16*)p; p += (size_t)C_ * C_ * 2;     //  2.1 MB
  u16* qb    = (u16*)p; p += (size_t)M_ * C_ * 2;     // 16.8 MB  [B,H,T,64]
  u16* kb    = (u16*)p; p += (size_t)M_ * C_ * 2;     // 16.8 MB  [B,H,T,64]
  u16* vtb   = (u16*)p; p += (size_t)M_ * C_ * 2;     // 16.8 MB  tile-major swizzled
  u16* aob   = (u16*)p; p += (size_t)M_ * C_ * 2;     // 16.8 MB  [B,T,C]

  const int ncast = (M_ * C_ + N1_ * C_ + C_ * C_) / 4;
  cast_all<<<(ncast + 255) / 256, 256, 0, stream>>>(x, wqkv, wo, xb, wqkvb, wob);

  gemm_bt<0><<<dim3(N1_ / 128, M_ / 128), 256, 0, stream>>>(xb, wqkvb, qb, kb, vtb, C_, N1_);

  // grid (bh, qb): flat%8 == bh%8 -> all q-blocks of a head on one XCD
  flash_kernel<<<dim3(B_ * H_, T_ / 128), 256, 0, stream>>>(qb, kb, vtb, aob);

  gemm_bt<1><<<dim3(C_ / 128, M_ / 128), 256, 0, stream>>>(aob, wob, d_out, nullptr, nullptr, C_, C_);
}

// Round 9
// 284.585 us; speedup vs baseline: 1.0379x; 1.0081x over previous
//
#include <hip/hip_runtime.h>
#include <hip/hip_bf16.h>
#include <stdint.h>

// MHA fwd: x[4,2048,1024] fp32, w_qkv[3072,1024], w_o[1024,1024]
// bf16 MFMA pipeline: cast -> QKV gemm (scale folded into q; V stored
// tile-major with 8B XOR swizzle) -> flash attention (S^T trick: P stays in
// registers, K=16 PV MFMAs, per-nj interleaved pipeline, 256-thr blocks with
// 64 q-rows PER WAVE so each staged K/V tile serves 256 rows, R7-proven
// double-buffered async staging, XCD-local grid) -> out gemm

#define B_   4
#define T_   2048
#define H_   16
#define DK_  64
#define C_   1024
#define M_   (B_*T_)    // 8192 rows
#define N1_  (3*C_)     // 3072
#define LOG2E 1.44269504088896340736f
#define SCFOLD (0.125f * LOG2E)   // folded into q at QKV epilogue

using short8  = __attribute__((ext_vector_type(8))) short;
using short4v = __attribute__((ext_vector_type(4))) short;
using f32x4   = __attribute__((ext_vector_type(4))) float;
typedef unsigned short u16;

__device__ __forceinline__ u16 f2bf(float f) {       // RNE (used in epilogues)
  unsigned u = __float_as_uint(f);
  u += 0x7FFF + ((u >> 16) & 1);
  return (u16)(u >> 16);
}

// exp2 + bf16-round + pack 4 floats -> short4v: 4 exp, 4 add, 2 perm (R7-proven)
__device__ __forceinline__ short4v packexp(f32x4 s) {
  unsigned u0 = __float_as_uint(__builtin_amdgcn_exp2f(s[0])) + 0x8000u;
  unsigned u1 = __float_as_uint(__builtin_amdgcn_exp2f(s[1])) + 0x8000u;
  unsigned u2 = __float_as_uint(__builtin_amdgcn_exp2f(s[2])) + 0x8000u;
  unsigned u3 = __float_as_uint(__builtin_amdgcn_exp2f(s[3])) + 0x8000u;
  union { unsigned w[2]; short4v s4; } cv;
  cv.w[0] = __builtin_amdgcn_perm(u1, u0, 0x07060302);  // {bf(u1),bf(u0)}
  cv.w[1] = __builtin_amdgcn_perm(u3, u2, 0x07060302);  // {bf(u3),bf(u2)}
  return cv.s4;
}

// async global->LDS, 16B per lane; lds ptr is wave-uniform base, HW adds lane*16
__device__ __forceinline__ void gld_lds16(void* lds, const void* g) {
  __builtin_amdgcn_global_load_lds(
      (__attribute__((address_space(1))) void*)(g),
      (__attribute__((address_space(3))) void*)(lds), 16, 0, 0);
}

// ---------------- fp32 -> bf16 cast (all three tensors, one launch) ----------
__global__ void cast_all(const float* __restrict__ x, const float* __restrict__ wq,
                         const float* __restrict__ wo, u16* __restrict__ xb,
                         u16* __restrict__ wqb, u16* __restrict__ wob) {
  const int nx = M_ * C_ / 4, nq = N1_ * C_ / 4;
  int i = blockIdx.x * blockDim.x + threadIdx.x;
  const float* src; u16* dst; int j;
  if (i < nx)            { src = x;  dst = xb;  j = i; }
  else if (i < nx + nq)  { src = wq; dst = wqb; j = i - nx; }
  else                   { src = wo; dst = wob; j = i - nx - nq; }
  float4 v = ((const float4*)src)[j];
  ushort4 o;
  o.x = f2bf(v.x); o.y = f2bf(v.y); o.z = f2bf(v.z); o.w = f2bf(v.w);
  ((ushort4*)dst)[j] = o;
}

// ---------------- BT GEMM: C[m,n] = sum_k A[m,k]*B[n,k] ----------------
// 128x128 tile, BK=32, 4 waves in 2x2, each wave 64x64 (4x4 MFMA 16x16x32).
// MODE 0: epilogue scatters qkv -> q[B,H,T,64] (pre-scaled by SCFOLD),
//         k[B,H,T,64], and V in flash-ready tile-major swizzled layout:
//         per (bh,kt) 64x16-unit tile; unit u=(t>>2)&15 at p = u^(d&15).
// MODE 1: epilogue writes fp32 C row-major [M,N]
template <int MODE>
__global__ __launch_bounds__(256)
void gemm_bt(const u16* __restrict__ A, const u16* __restrict__ Bm,
             void* __restrict__ out0, void* __restrict__ out1, void* __restrict__ out2,
             int K, int N) {
  __shared__ __attribute__((aligned(16))) u16 As[128 * 32];
  __shared__ __attribute__((aligned(16))) u16 Bs[128 * 32];
  const int tid  = threadIdx.x;
  const int w    = tid >> 6, lane = tid & 63;
  const int quad = lane >> 4, l15 = lane & 15;
  const int wm   = w >> 1, wn = w & 1;
  const int m0   = blockIdx.y * 128, n0 = blockIdx.x * 128;

  f32x4 acc[4][4];
#pragma unroll
  for (int i = 0; i < 4; i++)
#pragma unroll
    for (int j = 0; j < 4; j++) acc[i][j] = f32x4{0.f, 0.f, 0.f, 0.f};

  const int nkt = K >> 5;
  for (int kt = 0; kt < nkt; ++kt) {
    __syncthreads();
    // stage A,B tiles: 128x32 bf16 = 8KB each = 512 chunks of 16B
#pragma unroll
    for (int c = 0; c < 2; ++c) {
      int chunk = c * 256 + tid;
      int row = chunk >> 2, col = (chunk & 3) << 3;
      gld_lds16(As + (c * 256 + w * 64) * 8, A  + (size_t)(m0 + row) * K + kt * 32 + col);
      gld_lds16(Bs + (c * 256 + w * 64) * 8, Bm + (size_t)(n0 + row) * K + kt * 32 + col);
    }
    __syncthreads();
    short8 af[4], bf[4];
#pragma unroll
    for (int i = 0; i < 4; i++)
      af[i] = *(const short8*)(As + (wm * 64 + i * 16 + l15) * 32 + quad * 8);
#pragma unroll
    for (int j = 0; j < 4; j++)
      bf[j] = *(const short8*)(Bs + (wn * 64 + j * 16 + l15) * 32 + quad * 8);
#pragma unroll
    for (int i = 0; i < 4; i++)
#pragma unroll
      for (int j = 0; j < 4; j++)
        acc[i][j] = __builtin_amdgcn_mfma_f32_16x16x32_bf16(af[i], bf[j], acc[i][j], 0, 0, 0);
  }

  // epilogue: C/D layout col=lane&15, row=quad*4+reg  (m89-verified)
  if (MODE == 0) {
    u16* q  = (u16*)out0;
    u16* k  = (u16*)out1;
    u16* vt = (u16*)out2;
#pragma unroll
    for (int i = 0; i < 4; i++) {
      int m = m0 + wm * 64 + i * 16 + quad * 4;   // + r below, never crosses b boundary
      int b = m >> 11, t = m & 2047;              // t multiple of 4
#pragma unroll
      for (int j = 0; j < 4; j++) {
        int f = n0 + wn * 64 + j * 16 + l15;
        int s = f >> 10, h = (f >> 6) & 15, d = f & 63;
        if (s == 2) {
          ushort4 pk;                              // keys t..t+3 of dim d = one unit
          pk.x = f2bf(acc[i][j][0]); pk.y = f2bf(acc[i][j][1]);
          pk.z = f2bf(acc[i][j][2]); pk.w = f2bf(acc[i][j][3]);
          int kt2 = t >> 6;
          int u   = (t >> 2) & 15;
          int pp  = u ^ (d & 15);                  // 8B swizzle for bank-free reads
          *(ushort4*)(vt + ((((size_t)(b * H_ + h) * 32 + kt2) * 64 + d) * 16 + pp) * 4) = pk;
        } else {
          u16* dst = (s == 0) ? q : k;
          float sc = (s == 0) ? SCFOLD : 1.0f;
#pragma unroll
          for (int r = 0; r < 4; r++)
            dst[(((size_t)(b * H_ + h)) * T_ + (t + r)) * DK_ + d] = f2bf(acc[i][j][r] * sc);
        }
      }
    }
  } else {
    float* outp = (float*)out0;
#pragma unroll
    for (int i = 0; i < 4; i++) {
      int m = m0 + wm * 64 + i * 16 + quad * 4;
#pragma unroll
      for (int j = 0; j < 4; j++) {
        int n = n0 + wn * 64 + j * 16 + l15;
#pragma unroll
        for (int r = 0; r < 4; r++)
          outp[(size_t)(m + r) * N + n] = acc[i][j][r];
      }
    }
  }
}

// ---------------- flash attention (S^T / register-P / dbuf / interleaved) ----
// grid (B*H, T/256), 256 thr: flat%8 == bh%8 -> all q-blocks of a head on one
// XCD. 4 waves/block, wave w owns 64 Q-rows (4 x 16). KT=64 keys per iter.
// Each staged K/V tile serves 256 q-rows -> half the barriers and half the
// per-CU staging DMA of the 32-rows-per-wave version. Staging structure is
// byte-identical to the R7-verified kernel.
//
// S^T = K·Q^T via 16x16x32 (operand swap). S^T C-layout (q=l15, key=quad*4+r)
// IS the K=16 MFMA A-fragment layout -> exp(S^T) packs straight into
// mfma_f32_16x16x16bf16_1k A-operands for O += P·V, rowsum += P·1.
// K staged with 16B XOR source swizzle; V pre-swizzled in global (8B units,
// p = u^(d&15)) and staged linearly -> both at LDS bank floor.
__global__ __launch_bounds__(256)
void flash_kernel(const u16* __restrict__ Q, const u16* __restrict__ Kg,
                  const u16* __restrict__ Vt, u16* __restrict__ AO) {
  __shared__ __attribute__((aligned(16))) u16 KVs[2][2][64 * 64];  // [buf][K/V]
  const int tid  = threadIdx.x;
  const int w    = tid >> 6, lane = tid & 63;
  const int quad = lane >> 4, l15 = lane & 15;
  const int bh   = blockIdx.x;
  const int q0   = blockIdx.y * 256;
  const u16* Qb = Q  + (size_t)bh * T_ * DK_;
  const u16* Kb = Kg + (size_t)bh * T_ * DK_;
  const u16* Vb = Vt + (size_t)bh * T_ * DK_;   // 32 tiles x 4096 u16, contiguous

  // Q fragments (B-operand of S^T = K·Q^T): lane n=q=l15 holds d=quad*8+j.
  short8 qf[4][2];
#pragma unroll
  for (int mi = 0; mi < 4; mi++)
#pragma unroll
    for (int ks = 0; ks < 2; ks++)
      qf[mi][ks] = *(const short8*)(Qb + (size_t)(q0 + w * 64 + mi * 16 + l15) * DK_ + ks * 32 + quad * 8);

  // ones A/B-fragment (bf16 1.0 x4) for K=16 rowsum MFMA
  short4v ones;
#pragma unroll
  for (int z = 0; z < 4; z++) ones[z] = (short)0x3F80;

  f32x4 O[4][4];       // rows q=quad*4+r, cols d=dj*16+l15 (C/D layout)
  f32x4 rowsum[4];
#pragma unroll
  for (int mi = 0; mi < 4; mi++) {
    rowsum[mi] = f32x4{0.f, 0.f, 0.f, 0.f};
#pragma unroll
    for (int dj = 0; dj < 4; dj++) O[mi][dj] = f32x4{0.f, 0.f, 0.f, 0.f};
  }

  const int swz = l15 & 7;
  const int NT  = T_ / 64;
  // kt-invariant LDS read offsets (elements)
  const int koff0 = ((quad) ^ swz) * 8;            // ks=0 K chunk
  const int koff1 = ((4 + quad) ^ swz) * 8;        // ks=1 K chunk
  int voff[4];
#pragma unroll
  for (int nj = 0; nj < 4; nj++) voff[nj] = ((nj * 4 + quad) ^ l15) * 4;

  // stage tile kt into buffer b (async DMA). K: source-swizzled 16B chunks.
  // V: plain linear copy of the pre-swizzled 8KB tile.  (R7-verified code.)
  auto stage = [&](int kt, int b) {
#pragma unroll
    for (int c = 0; c < 2; ++c) {
      int s = c * 256 + tid;
      int row = s >> 3, cc = (s & 7) ^ (row & 7);
      gld_lds16(&KVs[b][0][(c * 256 + w * 64) * 8], Kb + (size_t)kt * 4096 + row * 64 + cc * 8);
      gld_lds16(&KVs[b][1][(c * 256 + w * 64) * 8], Vb + (size_t)kt * 4096 + s * 8);
    }
  };

  stage(0, 0);   // prologue

  for (int kt = 0; kt < NT; ++kt) {
    __syncthreads();               // DMA for buf[kt&1] landed during last iter
    if (kt + 1 < NT) stage(kt + 1, (kt + 1) & 1);   // hidden by compute below
    const u16* Ks = KVs[kt & 1][0];
    const u16* Vs = KVs[kt & 1][1];

    // 4 interleaved units: QK-MFMAs -> exp/pack -> rowsum+PV MFMAs (+ds reads)
#pragma unroll
    for (int nj = 0; nj < 4; nj++) {
      const u16* krow = Ks + (nj * 16 + l15) * 64;
      short8 kfr0 = *(const short8*)(krow + koff0);
      short8 kfr1 = *(const short8*)(krow + koff1);
      f32x4 st[4];
#pragma unroll
      for (int mi = 0; mi < 4; mi++) {
        st[mi] = f32x4{0.f, 0.f, 0.f, 0.f};
        st[mi] = __builtin_amdgcn_mfma_f32_16x16x32_bf16(kfr0, qf[mi][0], st[mi], 0, 0, 0);
        st[mi] = __builtin_amdgcn_mfma_f32_16x16x32_bf16(kfr1, qf[mi][1], st[mi], 0, 0, 0);
      }
      short4v pf[4];
#pragma unroll
      for (int mi = 0; mi < 4; mi++) pf[mi] = packexp(st[mi]);
#pragma unroll
      for (int mi = 0; mi < 4; mi++)
        rowsum[mi] = __builtin_amdgcn_mfma_f32_16x16x16bf16_1k(pf[mi], ones, rowsum[mi], 0, 0, 0);
#pragma unroll
      for (int dj = 0; dj < 4; dj++) {
        short4v vfr = *(const short4v*)(Vs + (dj * 16 + l15) * 64 + voff[nj]);
#pragma unroll
        for (int mi = 0; mi < 4; mi++)
          O[mi][dj] = __builtin_amdgcn_mfma_f32_16x16x16bf16_1k(pf[mi], vfr, O[mi][dj], 0, 0, 0);
      }
    }
  }

  // epilogue: rowsum[mi][r] holds the full key-sum for q-row quad*4+r
  const int b = bh >> 4, h = bh & 15;
#pragma unroll
  for (int mi = 0; mi < 4; mi++) {
#pragma unroll
    for (int r = 0; r < 4; r++) {
      float inv = 1.0f / rowsum[mi][r];
      int t = q0 + w * 64 + mi * 16 + quad * 4 + r;
#pragma unroll
      for (int dj = 0; dj < 4; dj++)
        AO[((size_t)(b * T_ + t)) * C_ + h * DK_ + dj * 16 + l15] = f2bf(O[mi][dj][r] * inv);
    }
  }
}

extern "C" void kernel_launch(void* const* d_in, const int* in_sizes, int n_in,
                              void* d_out, int out_size, void* d_ws, size_t ws_size,
                              hipStream_t stream) {
  const float* x    = (const float*)d_in[0];
  const float* wqkv = (const float*)d_in[1];
  const float* wo   = (const float*)d_in[2];

  char* p = (char*)d_ws;
  u16* xb    = (u16*)p; p += (size_t)M_ * C_ * 2;     // 16.8 MB
  u16* wqkvb = (u16*)p; p += (size_t)N1_ * C_ * 2;    //  6.3 MB
  u16* wob   = (u16*)p; p += (size_t)C_ * C_ * 2;     //  2.1 MB
  u16* qb    = (u16*)p; p += (size_t)M_ * C_ * 2;     // 16.8 MB  [B,H,T,64]
  u16* kb    = (u16*)p; p += (size_t)M_ * C_ * 2;     // 16.8 MB  [B,H,T,64]
  u16* vtb   = (u16*)p; p += (size_t)M_ * C_ * 2;     // 16.8 MB  tile-major swizzled
  u16* aob   = (u16*)p; p += (size_t)M_ * C_ * 2;     // 16.8 MB  [B,T,C]

  const int ncast = (M_ * C_ + N1_ * C_ + C_ * C_) / 4;
  cast_all<<<(ncast + 255) / 256, 256, 0, stream>>>(x, wqkv, wo, xb, wqkvb, wob);

  gemm_bt<0><<<dim3(N1_ / 128, M_ / 128), 256, 0, stream>>>(xb, wqkvb, qb, kb, vtb, C_, N1_);

  // grid (bh, qb): flat%8 == bh%8 -> all q-blocks of a head on one XCD
  flash_kernel<<<dim3(B_ * H_, T_ / 256), 256, 0, stream>>>(qb, kb, vtb, aob);

  gemm_bt<1><<<dim3(C_ / 128, M_ / 128), 256, 0, stream>>>(aob, wob, d_out, nullptr, nullptr, C_, C_);
}

// Round 10
// 283.792 us; speedup vs baseline: 1.0408x; 1.0028x over previous
//
#include <hip/hip_runtime.h>
#include <hip/hip_bf16.h>
#include <stdint.h>

// MHA fwd: x[4,2048,1024] fp32, w_qkv[3072,1024], w_o[1024,1024]
// bf16 MFMA pipeline: cast -> QKV gemm (scale folded into q; V stored
// tile-major with 8B XOR swizzle) -> flash attention (R7-proven structure:
// S^T trick, register-P, K=16 PV MFMAs, per-nj interleave, 4 waves x 32 rows,
// dbuf async staging, XCD-local grid; truncating P-pack) -> out gemm

#define B_   4
#define T_   2048
#define H_   16
#define DK_  64
#define C_   1024
#define M_   (B_*T_)    // 8192 rows
#define N1_  (3*C_)     // 3072
#define LOG2E 1.44269504088896340736f
#define SCFOLD (0.125f * LOG2E)   // folded into q at QKV epilogue

using short8  = __attribute__((ext_vector_type(8))) short;
using short4v = __attribute__((ext_vector_type(4))) short;
using f32x4   = __attribute__((ext_vector_type(4))) float;
typedef unsigned short u16;

__device__ __forceinline__ u16 f2bf(float f) {       // RNE (used in epilogues)
  unsigned u = __float_as_uint(f);
  u += 0x7FFF + ((u >> 16) & 1);
  return (u16)(u >> 16);
}

// exp2 + TRUNCATE-to-bf16 + pack 4 floats -> short4v: 4 exp + 2 perm.
// NaN-safe: exp2 outputs are positive normals; hi16 truncation yields a valid
// bf16 <= exact. Downward bias (<2^-9 rel) hits P·V and P·1 coherently, so
// the normalized O ratio keeps only the ±2^-9 cross-key spread (~RNE noise).
__device__ __forceinline__ short4v packexp(f32x4 s) {
  unsigned u0 = __float_as_uint(__builtin_amdgcn_exp2f(s[0]));
  unsigned u1 = __float_as_uint(__builtin_amdgcn_exp2f(s[1]));
  unsigned u2 = __float_as_uint(__builtin_amdgcn_exp2f(s[2]));
  unsigned u3 = __float_as_uint(__builtin_amdgcn_exp2f(s[3]));
  union { unsigned w[2]; short4v s4; } cv;
  cv.w[0] = __builtin_amdgcn_perm(u1, u0, 0x07060302);  // {hi16(u1),hi16(u0)}
  cv.w[1] = __builtin_amdgcn_perm(u3, u2, 0x07060302);  // {hi16(u3),hi16(u2)}
  return cv.s4;
}

// async global->LDS, 16B per lane; lds ptr is wave-uniform base, HW adds lane*16
__device__ __forceinline__ void gld_lds16(void* lds, const void* g) {
  __builtin_amdgcn_global_load_lds(
      (__attribute__((address_space(1))) void*)(g),
      (__attribute__((address_space(3))) void*)(lds), 16, 0, 0);
}

// ---------------- fp32 -> bf16 cast (all three tensors, one launch) ----------
__global__ void cast_all(const float* __restrict__ x, const float* __restrict__ wq,
                         const float* __restrict__ wo, u16* __restrict__ xb,
                         u16* __restrict__ wqb, u16* __restrict__ wob) {
  const int nx = M_ * C_ / 4, nq = N1_ * C_ / 4;
  int i = blockIdx.x * blockDim.x + threadIdx.x;
  const float* src; u16* dst; int j;
  if (i < nx)            { src = x;  dst = xb;  j = i; }
  else if (i < nx + nq)  { src = wq; dst = wqb; j = i - nx; }
  else                   { src = wo; dst = wob; j = i - nx - nq; }
  float4 v = ((const float4*)src)[j];
  ushort4 o;
  o.x = f2bf(v.x); o.y = f2bf(v.y); o.z = f2bf(v.z); o.w = f2bf(v.w);
  ((ushort4*)dst)[j] = o;
}

// ---------------- BT GEMM: C[m,n] = sum_k A[m,k]*B[n,k] ----------------
// 128x128 tile, BK=32, 4 waves in 2x2, each wave 64x64 (4x4 MFMA 16x16x32).
// MODE 0: epilogue scatters qkv -> q[B,H,T,64] (pre-scaled by SCFOLD),
//         k[B,H,T,64], and V in flash-ready tile-major swizzled layout:
//         per (bh,kt) 64x16-unit tile; unit u=(t>>2)&15 at p = u^(d&15).
// MODE 1: epilogue writes fp32 C row-major [M,N]
template <int MODE>
__global__ __launch_bounds__(256)
void gemm_bt(const u16* __restrict__ A, const u16* __restrict__ Bm,
             void* __restrict__ out0, void* __restrict__ out1, void* __restrict__ out2,
             int K, int N) {
  __shared__ __attribute__((aligned(16))) u16 As[128 * 32];
  __shared__ __attribute__((aligned(16))) u16 Bs[128 * 32];
  const int tid  = threadIdx.x;
  const int w    = tid >> 6, lane = tid & 63;
  const int quad = lane >> 4, l15 = lane & 15;
  const int wm   = w >> 1, wn = w & 1;
  const int m0   = blockIdx.y * 128, n0 = blockIdx.x * 128;

  f32x4 acc[4][4];
#pragma unroll
  for (int i = 0; i < 4; i++)
#pragma unroll
    for (int j = 0; j < 4; j++) acc[i][j] = f32x4{0.f, 0.f, 0.f, 0.f};

  const int nkt = K >> 5;
  for (int kt = 0; kt < nkt; ++kt) {
    __syncthreads();
    // stage A,B tiles: 128x32 bf16 = 8KB each = 512 chunks of 16B
#pragma unroll
    for (int c = 0; c < 2; ++c) {
      int chunk = c * 256 + tid;
      int row = chunk >> 2, col = (chunk & 3) << 3;
      gld_lds16(As + (c * 256 + w * 64) * 8, A  + (size_t)(m0 + row) * K + kt * 32 + col);
      gld_lds16(Bs + (c * 256 + w * 64) * 8, Bm + (size_t)(n0 + row) * K + kt * 32 + col);
    }
    __syncthreads();
    short8 af[4], bf[4];
#pragma unroll
    for (int i = 0; i < 4; i++)
      af[i] = *(const short8*)(As + (wm * 64 + i * 16 + l15) * 32 + quad * 8);
#pragma unroll
    for (int j = 0; j < 4; j++)
      bf[j] = *(const short8*)(Bs + (wn * 64 + j * 16 + l15) * 32 + quad * 8);
#pragma unroll
    for (int i = 0; i < 4; i++)
#pragma unroll
      for (int j = 0; j < 4; j++)
        acc[i][j] = __builtin_amdgcn_mfma_f32_16x16x32_bf16(af[i], bf[j], acc[i][j], 0, 0, 0);
  }

  // epilogue: C/D layout col=lane&15, row=quad*4+reg  (m89-verified)
  if (MODE == 0) {
    u16* q  = (u16*)out0;
    u16* k  = (u16*)out1;
    u16* vt = (u16*)out2;
#pragma unroll
    for (int i = 0; i < 4; i++) {
      int m = m0 + wm * 64 + i * 16 + quad * 4;   // + r below, never crosses b boundary
      int b = m >> 11, t = m & 2047;              // t multiple of 4
#pragma unroll
      for (int j = 0; j < 4; j++) {
        int f = n0 + wn * 64 + j * 16 + l15;
        int s = f >> 10, h = (f >> 6) & 15, d = f & 63;
        if (s == 2) {
          ushort4 pk;                              // keys t..t+3 of dim d = one unit
          pk.x = f2bf(acc[i][j][0]); pk.y = f2bf(acc[i][j][1]);
          pk.z = f2bf(acc[i][j][2]); pk.w = f2bf(acc[i][j][3]);
          int kt2 = t >> 6;
          int u   = (t >> 2) & 15;
          int pp  = u ^ (d & 15);                  // 8B swizzle for bank-free reads
          *(ushort4*)(vt + ((((size_t)(b * H_ + h) * 32 + kt2) * 64 + d) * 16 + pp) * 4) = pk;
        } else {
          u16* dst = (s == 0) ? q : k;
          float sc = (s == 0) ? SCFOLD : 1.0f;
#pragma unroll
          for (int r = 0; r < 4; r++)
            dst[(((size_t)(b * H_ + h)) * T_ + (t + r)) * DK_ + d] = f2bf(acc[i][j][r] * sc);
        }
      }
    }
  } else {
    float* outp = (float*)out0;
#pragma unroll
    for (int i = 0; i < 4; i++) {
      int m = m0 + wm * 64 + i * 16 + quad * 4;
#pragma unroll
      for (int j = 0; j < 4; j++) {
        int n = n0 + wn * 64 + j * 16 + l15;
#pragma unroll
        for (int r = 0; r < 4; r++)
          outp[(size_t)(m + r) * N + n] = acc[i][j][r];
      }
    }
  }
}

// ---------------- flash attention (R7 structure, exact) ----------------
// grid (B*H, T/128), 256 thr: flat%8 == bh%8 -> all q-blocks of a head on one
// XCD. 4 waves/block (4 blocks/CU, 16 waves/CU — the measured sweet spot;
// R8/R9 showed both 8-wave blocks and 2-blocks/CU regress). Wave w owns 32
// Q-rows (2 x 16). KT=64 keys per iter.
//
// S^T = K·Q^T via 16x16x32 (operand swap). S^T C-layout (q=l15, key=quad*4+r)
// IS the K=16 MFMA A-fragment layout -> exp(S^T) packs straight into
// mfma_f32_16x16x16bf16_1k A-operands for O += P·V, rowsum += P·1.
// K staged with 16B XOR source swizzle; V pre-swizzled in global (8B units,
// p = u^(d&15)) and staged linearly -> both at LDS bank floor.
__global__ __launch_bounds__(256)
void flash_kernel(const u16* __restrict__ Q, const u16* __restrict__ Kg,
                  const u16* __restrict__ Vt, u16* __restrict__ AO) {
  __shared__ __attribute__((aligned(16))) u16 KVs[2][2][64 * 64];  // [buf][K/V]
  const int tid  = threadIdx.x;
  const int w    = tid >> 6, lane = tid & 63;
  const int quad = lane >> 4, l15 = lane & 15;
  const int bh   = blockIdx.x;
  const int q0   = blockIdx.y * 128;
  const u16* Qb = Q  + (size_t)bh * T_ * DK_;
  const u16* Kb = Kg + (size_t)bh * T_ * DK_;
  const u16* Vb = Vt + (size_t)bh * T_ * DK_;   // 32 tiles x 4096 u16, contiguous

  // Q fragments (B-operand of S^T = K·Q^T): lane n=q=l15 holds d=quad*8+j.
  short8 qf[2][2];
#pragma unroll
  for (int mi = 0; mi < 2; mi++)
#pragma unroll
    for (int ks = 0; ks < 2; ks++)
      qf[mi][ks] = *(const short8*)(Qb + (size_t)(q0 + w * 32 + mi * 16 + l15) * DK_ + ks * 32 + quad * 8);

  // ones A/B-fragment (bf16 1.0 x4) for K=16 rowsum MFMA
  short4v ones;
#pragma unroll
  for (int z = 0; z < 4; z++) ones[z] = (short)0x3F80;

  f32x4 O[2][4];       // rows q=quad*4+r, cols d=dj*16+l15 (C/D layout)
  f32x4 rowsum[2];
#pragma unroll
  for (int mi = 0; mi < 2; mi++) {
    rowsum[mi] = f32x4{0.f, 0.f, 0.f, 0.f};
#pragma unroll
    for (int dj = 0; dj < 4; dj++) O[mi][dj] = f32x4{0.f, 0.f, 0.f, 0.f};
  }

  const int swz = l15 & 7;
  const int NT  = T_ / 64;
  // kt-invariant LDS read offsets (elements)
  const int koff0 = ((quad) ^ swz) * 8;            // ks=0 K chunk
  const int koff1 = ((4 + quad) ^ swz) * 8;        // ks=1 K chunk
  int voff[4];
#pragma unroll
  for (int nj = 0; nj < 4; nj++) voff[nj] = ((nj * 4 + quad) ^ l15) * 4;

  // stage tile kt into buffer b (async DMA). K: source-swizzled 16B chunks.
  // V: plain linear copy of the pre-swizzled 8KB tile.
  auto stage = [&](int kt, int b) {
#pragma unroll
    for (int c = 0; c < 2; ++c) {
      int s = c * 256 + tid;
      int row = s >> 3, cc = (s & 7) ^ (row & 7);
      gld_lds16(&KVs[b][0][(c * 256 + w * 64) * 8], Kb + (size_t)kt * 4096 + row * 64 + cc * 8);
      gld_lds16(&KVs[b][1][(c * 256 + w * 64) * 8], Vb + (size_t)kt * 4096 + s * 8);
    }
  };

  stage(0, 0);   // prologue

  for (int kt = 0; kt < NT; ++kt) {
    __syncthreads();               // DMA for buf[kt&1] landed during last iter
    if (kt + 1 < NT) stage(kt + 1, (kt + 1) & 1);   // hidden by compute below
    const u16* Ks = KVs[kt & 1][0];
    const u16* Vs = KVs[kt & 1][1];

    // 4 interleaved units: QK-MFMA -> exp/pack -> rowsum+PV MFMAs (+ds reads)
#pragma unroll
    for (int nj = 0; nj < 4; nj++) {
      const u16* krow = Ks + (nj * 16 + l15) * 64;
      short8 kfr0 = *(const short8*)(krow + koff0);
      short8 kfr1 = *(const short8*)(krow + koff1);
      f32x4 st0 = f32x4{0.f, 0.f, 0.f, 0.f};
      f32x4 st1 = f32x4{0.f, 0.f, 0.f, 0.f};
      st0 = __builtin_amdgcn_mfma_f32_16x16x32_bf16(kfr0, qf[0][0], st0, 0, 0, 0);
      st0 = __builtin_amdgcn_mfma_f32_16x16x32_bf16(kfr1, qf[0][1], st0, 0, 0, 0);
      st1 = __builtin_amdgcn_mfma_f32_16x16x32_bf16(kfr0, qf[1][0], st1, 0, 0, 0);
      st1 = __builtin_amdgcn_mfma_f32_16x16x32_bf16(kfr1, qf[1][1], st1, 0, 0, 0);
      short4v pf0 = packexp(st0);
      short4v pf1 = packexp(st1);
      rowsum[0] = __builtin_amdgcn_mfma_f32_16x16x16bf16_1k(pf0, ones, rowsum[0], 0, 0, 0);
      rowsum[1] = __builtin_amdgcn_mfma_f32_16x16x16bf16_1k(pf1, ones, rowsum[1], 0, 0, 0);
#pragma unroll
      for (int dj = 0; dj < 4; dj++) {
        short4v vfr = *(const short4v*)(Vs + (dj * 16 + l15) * 64 + voff[nj]);
        O[0][dj] = __builtin_amdgcn_mfma_f32_16x16x16bf16_1k(pf0, vfr, O[0][dj], 0, 0, 0);
        O[1][dj] = __builtin_amdgcn_mfma_f32_16x16x16bf16_1k(pf1, vfr, O[1][dj], 0, 0, 0);
      }
    }
  }

  // epilogue: rowsum[mi][r] holds the full key-sum for q-row quad*4+r
  const int b = bh >> 4, h = bh & 15;
#pragma unroll
  for (int mi = 0; mi < 2; mi++) {
#pragma unroll
    for (int r = 0; r < 4; r++) {
      float inv = 1.0f / rowsum[mi][r];
      int t = q0 + w * 32 + mi * 16 + quad * 4 + r;
#pragma unroll
      for (int dj = 0; dj < 4; dj++)
        AO[((size_t)(b * T_ + t)) * C_ + h * DK_ + dj * 16 + l15] = f2bf(O[mi][dj][r] * inv);
    }
  }
}

extern "C" void kernel_launch(void* const* d_in, const int* in_sizes, int n_in,
                              void* d_out, int out_size, void* d_ws, size_t ws_size,
                              hipStream_t stream) {
  const float* x    = (const float*)d_in[0];
  const float* wqkv = (const float*)d_in[1];
  const float* wo   = (const float*)d_in[2];

  char* p = (char*)d_ws;
  u16* xb    = (u16*)p; p += (size_t)M_ * C_ * 2;     // 16.8 MB
  u16* wqkvb = (u16*)p; p += (size_t)N1_ * C_ * 2;    //  6.3 MB
  u16* wob   = (u16*)p; p += (size_t)C_ * C_ * 2;     //  2.1 MB
  u16* qb    = (u16*)p; p += (size_t)M_ * C_ * 2;     // 16.8 MB  [B,H,T,64]
  u16* kb    = (u16*)p; p += (size_t)M_ * C_ * 2;     // 16.8 MB  [B,H,T,64]
  u16* vtb   = (u16*)p; p += (size_t)M_ * C_ * 2;     // 16.8 MB  tile-major swizzled
  u16* aob   = (u16*)p; p += (size_t)M_ * C_ * 2;     // 16.8 MB  [B,T,C]

  const int ncast = (M_ * C_ + N1_ * C_ + C_ * C_) / 4;
  cast_all<<<(ncast + 255) / 256, 256, 0, stream>>>(x, wqkv, wo, xb, wqkvb, wob);

  gemm_bt<0><<<dim3(N1_ / 128, M_ / 128), 256, 0, stream>>>(xb, wqkvb, qb, kb, vtb, C_, N1_);

  // grid (bh, qb): flat%8 == bh%8 -> all q-blocks of a head on one XCD
  flash_kernel<<<dim3(B_ * H_, T_ / 128), 256, 0, stream>>>(qb, kb, vtb, aob);

  gemm_bt<1><<<dim3(C_ / 128, M_ / 128), 256, 0, stream>>>(aob, wob, d_out, nullptr, nullptr, C_, C_);
}

// Round 11
// 281.483 us; speedup vs baseline: 1.0493x; 1.0082x over previous
//
#include <hip/hip_runtime.h>
#include <hip/hip_bf16.h>
#include <stdint.h>

// MHA fwd: x[4,2048,1024] fp32, w_qkv[3072,1024], w_o[1024,1024]
// bf16 MFMA pipeline: cast -> QKV gemm (scale folded into q; V stored
// tile-major with 8B XOR swizzle) -> flash attention (R7 structure + nj
// software-pipeline: QK MFMAs of unit nj+1 issue before exp/PV of unit nj so
// trans-pipe work hides under MFMA-pipe work within each wave) -> out gemm

#define B_   4
#define T_   2048
#define H_   16
#define DK_  64
#define C_   1024
#define M_   (B_*T_)    // 8192 rows
#define N1_  (3*C_)     // 3072
#define LOG2E 1.44269504088896340736f
#define SCFOLD (0.125f * LOG2E)   // folded into q at QKV epilogue

using short8  = __attribute__((ext_vector_type(8))) short;
using short4v = __attribute__((ext_vector_type(4))) short;
using f32x4   = __attribute__((ext_vector_type(4))) float;
typedef unsigned short u16;

__device__ __forceinline__ u16 f2bf(float f) {       // RNE (used in epilogues)
  unsigned u = __float_as_uint(f);
  u += 0x7FFF + ((u >> 16) & 1);
  return (u16)(u >> 16);
}

// exp2 + TRUNCATE-to-bf16 + pack 4 floats -> short4v: 4 exp + 2 perm.
// NaN-safe: exp2 outputs are positive normals; hi16 truncation yields a valid
// bf16 <= exact. Downward bias (<2^-9 rel) hits P·V and P·1 coherently.
__device__ __forceinline__ short4v packexp(f32x4 s) {
  unsigned u0 = __float_as_uint(__builtin_amdgcn_exp2f(s[0]));
  unsigned u1 = __float_as_uint(__builtin_amdgcn_exp2f(s[1]));
  unsigned u2 = __float_as_uint(__builtin_amdgcn_exp2f(s[2]));
  unsigned u3 = __float_as_uint(__builtin_amdgcn_exp2f(s[3]));
  union { unsigned w[2]; short4v s4; } cv;
  cv.w[0] = __builtin_amdgcn_perm(u1, u0, 0x07060302);  // {hi16(u1),hi16(u0)}
  cv.w[1] = __builtin_amdgcn_perm(u3, u2, 0x07060302);  // {hi16(u3),hi16(u2)}
  return cv.s4;
}

// async global->LDS, 16B per lane; lds ptr is wave-uniform base, HW adds lane*16
__device__ __forceinline__ void gld_lds16(void* lds, const void* g) {
  __builtin_amdgcn_global_load_lds(
      (__attribute__((address_space(1))) void*)(g),
      (__attribute__((address_space(3))) void*)(lds), 16, 0, 0);
}

// ---------------- fp32 -> bf16 cast (all three tensors, one launch) ----------
__global__ void cast_all(const float* __restrict__ x, const float* __restrict__ wq,
                         const float* __restrict__ wo, u16* __restrict__ xb,
                         u16* __restrict__ wqb, u16* __restrict__ wob) {
  const int nx = M_ * C_ / 4, nq = N1_ * C_ / 4;
  int i = blockIdx.x * blockDim.x + threadIdx.x;
  const float* src; u16* dst; int j;
  if (i < nx)            { src = x;  dst = xb;  j = i; }
  else if (i < nx + nq)  { src = wq; dst = wqb; j = i - nx; }
  else                   { src = wo; dst = wob; j = i - nx - nq; }
  float4 v = ((const float4*)src)[j];
  ushort4 o;
  o.x = f2bf(v.x); o.y = f2bf(v.y); o.z = f2bf(v.z); o.w = f2bf(v.w);
  ((ushort4*)dst)[j] = o;
}

// ---------------- BT GEMM: C[m,n] = sum_k A[m,k]*B[n,k] ----------------
// 128x128 tile, BK=32, 4 waves in 2x2, each wave 64x64 (4x4 MFMA 16x16x32).
// MODE 0: epilogue scatters qkv -> q[B,H,T,64] (pre-scaled by SCFOLD),
//         k[B,H,T,64], and V in flash-ready tile-major swizzled layout:
//         per (bh,kt) 64x16-unit tile; unit u=(t>>2)&15 at p = u^(d&15).
// MODE 1: epilogue writes fp32 C row-major [M,N]
template <int MODE>
__global__ __launch_bounds__(256)
void gemm_bt(const u16* __restrict__ A, const u16* __restrict__ Bm,
             void* __restrict__ out0, void* __restrict__ out1, void* __restrict__ out2,
             int K, int N) {
  __shared__ __attribute__((aligned(16))) u16 As[128 * 32];
  __shared__ __attribute__((aligned(16))) u16 Bs[128 * 32];
  const int tid  = threadIdx.x;
  const int w    = tid >> 6, lane = tid & 63;
  const int quad = lane >> 4, l15 = lane & 15;
  const int wm   = w >> 1, wn = w & 1;
  const int m0   = blockIdx.y * 128, n0 = blockIdx.x * 128;

  f32x4 acc[4][4];
#pragma unroll
  for (int i = 0; i < 4; i++)
#pragma unroll
    for (int j = 0; j < 4; j++) acc[i][j] = f32x4{0.f, 0.f, 0.f, 0.f};

  const int nkt = K >> 5;
  for (int kt = 0; kt < nkt; ++kt) {
    __syncthreads();
    // stage A,B tiles: 128x32 bf16 = 8KB each = 512 chunks of 16B
#pragma unroll
    for (int c = 0; c < 2; ++c) {
      int chunk = c * 256 + tid;
      int row = chunk >> 2, col = (chunk & 3) << 3;
      gld_lds16(As + (c * 256 + w * 64) * 8, A  + (size_t)(m0 + row) * K + kt * 32 + col);
      gld_lds16(Bs + (c * 256 + w * 64) * 8, Bm + (size_t)(n0 + row) * K + kt * 32 + col);
    }
    __syncthreads();
    short8 af[4], bf[4];
#pragma unroll
    for (int i = 0; i < 4; i++)
      af[i] = *(const short8*)(As + (wm * 64 + i * 16 + l15) * 32 + quad * 8);
#pragma unroll
    for (int j = 0; j < 4; j++)
      bf[j] = *(const short8*)(Bs + (wn * 64 + j * 16 + l15) * 32 + quad * 8);
#pragma unroll
    for (int i = 0; i < 4; i++)
#pragma unroll
      for (int j = 0; j < 4; j++)
        acc[i][j] = __builtin_amdgcn_mfma_f32_16x16x32_bf16(af[i], bf[j], acc[i][j], 0, 0, 0);
  }

  // epilogue: C/D layout col=lane&15, row=quad*4+reg  (m89-verified)
  if (MODE == 0) {
    u16* q  = (u16*)out0;
    u16* k  = (u16*)out1;
    u16* vt = (u16*)out2;
#pragma unroll
    for (int i = 0; i < 4; i++) {
      int m = m0 + wm * 64 + i * 16 + quad * 4;   // + r below, never crosses b boundary
      int b = m >> 11, t = m & 2047;              // t multiple of 4
#pragma unroll
      for (int j = 0; j < 4; j++) {
        int f = n0 + wn * 64 + j * 16 + l15;
        int s = f >> 10, h = (f >> 6) & 15, d = f & 63;
        if (s == 2) {
          ushort4 pk;                              // keys t..t+3 of dim d = one unit
          pk.x = f2bf(acc[i][j][0]); pk.y = f2bf(acc[i][j][1]);
          pk.z = f2bf(acc[i][j][2]); pk.w = f2bf(acc[i][j][3]);
          int kt2 = t >> 6;
          int u   = (t >> 2) & 15;
          int pp  = u ^ (d & 15);                  // 8B swizzle for bank-free reads
          *(ushort4*)(vt + ((((size_t)(b * H_ + h) * 32 + kt2) * 64 + d) * 16 + pp) * 4) = pk;
        } else {
          u16* dst = (s == 0) ? q : k;
          float sc = (s == 0) ? SCFOLD : 1.0f;
#pragma unroll
          for (int r = 0; r < 4; r++)
            dst[(((size_t)(b * H_ + h)) * T_ + (t + r)) * DK_ + d] = f2bf(acc[i][j][r] * sc);
        }
      }
    }
  } else {
    float* outp = (float*)out0;
#pragma unroll
    for (int i = 0; i < 4; i++) {
      int m = m0 + wm * 64 + i * 16 + quad * 4;
#pragma unroll
      for (int j = 0; j < 4; j++) {
        int n = n0 + wn * 64 + j * 16 + l15;
#pragma unroll
        for (int r = 0; r < 4; r++)
          outp[(size_t)(m + r) * N + n] = acc[i][j][r];
      }
    }
  }
}

// ---------------- flash attention (R7 structure + nj software pipeline) ------
// grid (B*H, T/128), 256 thr: flat%8 == bh%8 -> all q-blocks of a head on one
// XCD. 4 waves/block (4 blocks/CU — measured sweet spot; R8/R9 showed both
// 8-wave blocks and 2-blocks/CU regress). Wave w owns 32 Q-rows (2 x 16).
//
// S^T = K·Q^T via 16x16x32 (operand swap). S^T C-layout (q=l15, key=quad*4+r)
// IS the K=16 MFMA A-fragment layout -> exp(S^T) packs straight into
// mfma_f32_16x16x16bf16_1k A-operands for O += P·V, rowsum += P·1.
// The nj loop is SOFTWARE-PIPELINED: QK MFMAs + K ds_reads of unit nj+1 are
// issued before the exp/pack/PV of unit nj. Units are independent, so while
// the trans pipe executes unit nj's 8 exps, the MFMA pipe executes unit
// nj+1's QK — per-wave overlap that doesn't rely on wave drift (R10 counters
// showed MFMA+VALU demands summing, i.e. zero overlap in the phase-locked
// ordering). K staged with 16B XOR source swizzle; V pre-swizzled in global
// (8B units, p = u^(d&15)) and staged linearly -> both at LDS bank floor.
__global__ __launch_bounds__(256)
void flash_kernel(const u16* __restrict__ Q, const u16* __restrict__ Kg,
                  const u16* __restrict__ Vt, u16* __restrict__ AO) {
  __shared__ __attribute__((aligned(16))) u16 KVs[2][2][64 * 64];  // [buf][K/V]
  const int tid  = threadIdx.x;
  const int w    = tid >> 6, lane = tid & 63;
  const int quad = lane >> 4, l15 = lane & 15;
  const int bh   = blockIdx.x;
  const int q0   = blockIdx.y * 128;
  const u16* Qb = Q  + (size_t)bh * T_ * DK_;
  const u16* Kb = Kg + (size_t)bh * T_ * DK_;
  const u16* Vb = Vt + (size_t)bh * T_ * DK_;   // 32 tiles x 4096 u16, contiguous

  // Q fragments (B-operand of S^T = K·Q^T): lane n=q=l15 holds d=quad*8+j.
  short8 qf[2][2];
#pragma unroll
  for (int mi = 0; mi < 2; mi++)
#pragma unroll
    for (int ks = 0; ks < 2; ks++)
      qf[mi][ks] = *(const short8*)(Qb + (size_t)(q0 + w * 32 + mi * 16 + l15) * DK_ + ks * 32 + quad * 8);

  // ones A/B-fragment (bf16 1.0 x4) for K=16 rowsum MFMA
  short4v ones;
#pragma unroll
  for (int z = 0; z < 4; z++) ones[z] = (short)0x3F80;

  f32x4 O[2][4];       // rows q=quad*4+r, cols d=dj*16+l15 (C/D layout)
  f32x4 rowsum[2];
#pragma unroll
  for (int mi = 0; mi < 2; mi++) {
    rowsum[mi] = f32x4{0.f, 0.f, 0.f, 0.f};
#pragma unroll
    for (int dj = 0; dj < 4; dj++) O[mi][dj] = f32x4{0.f, 0.f, 0.f, 0.f};
  }

  const int swz = l15 & 7;
  const int NT  = T_ / 64;
  // kt-invariant LDS read offsets (elements)
  const int koff0 = ((quad) ^ swz) * 8;            // ks=0 K chunk
  const int koff1 = ((4 + quad) ^ swz) * 8;        // ks=1 K chunk
  int voff[4];
#pragma unroll
  for (int nj = 0; nj < 4; nj++) voff[nj] = ((nj * 4 + quad) ^ l15) * 4;

  // stage tile kt into buffer b (async DMA). K: source-swizzled 16B chunks.
  // V: plain linear copy of the pre-swizzled 8KB tile.
  auto stage = [&](int kt, int b) {
#pragma unroll
    for (int c = 0; c < 2; ++c) {
      int s = c * 256 + tid;
      int row = s >> 3, cc = (s & 7) ^ (row & 7);
      gld_lds16(&KVs[b][0][(c * 256 + w * 64) * 8], Kb + (size_t)kt * 4096 + row * 64 + cc * 8);
      gld_lds16(&KVs[b][1][(c * 256 + w * 64) * 8], Vb + (size_t)kt * 4096 + s * 8);
    }
  };

  stage(0, 0);   // prologue

  for (int kt = 0; kt < NT; ++kt) {
    __syncthreads();               // DMA for buf[kt&1] landed during last iter
    if (kt + 1 < NT) stage(kt + 1, (kt + 1) & 1);   // hidden by compute below
    const u16* Ks = KVs[kt & 1][0];
    const u16* Vs = KVs[kt & 1][1];

    // pipeline prologue: QK for unit 0
    f32x4 stc0, stc1, stn0, stn1;
    {
      const u16* krow = Ks + l15 * 64;
      short8 kfr0 = *(const short8*)(krow + koff0);
      short8 kfr1 = *(const short8*)(krow + koff1);
      stc0 = f32x4{0.f, 0.f, 0.f, 0.f};
      stc1 = f32x4{0.f, 0.f, 0.f, 0.f};
      stc0 = __builtin_amdgcn_mfma_f32_16x16x32_bf16(kfr0, qf[0][0], stc0, 0, 0, 0);
      stc0 = __builtin_amdgcn_mfma_f32_16x16x32_bf16(kfr1, qf[0][1], stc0, 0, 0, 0);
      stc1 = __builtin_amdgcn_mfma_f32_16x16x32_bf16(kfr0, qf[1][0], stc1, 0, 0, 0);
      stc1 = __builtin_amdgcn_mfma_f32_16x16x32_bf16(kfr1, qf[1][1], stc1, 0, 0, 0);
    }
#pragma unroll
    for (int nj = 0; nj < 4; nj++) {
      // issue next unit's QK MFMAs FIRST — they execute on the MFMA pipe
      // while this unit's exps run on the trans pipe.
      if (nj < 3) {
        const u16* krow = Ks + ((nj + 1) * 16 + l15) * 64;
        short8 kfr0 = *(const short8*)(krow + koff0);
        short8 kfr1 = *(const short8*)(krow + koff1);
        stn0 = f32x4{0.f, 0.f, 0.f, 0.f};
        stn1 = f32x4{0.f, 0.f, 0.f, 0.f};
        stn0 = __builtin_amdgcn_mfma_f32_16x16x32_bf16(kfr0, qf[0][0], stn0, 0, 0, 0);
        stn0 = __builtin_amdgcn_mfma_f32_16x16x32_bf16(kfr1, qf[0][1], stn0, 0, 0, 0);
        stn1 = __builtin_amdgcn_mfma_f32_16x16x32_bf16(kfr0, qf[1][0], stn1, 0, 0, 0);
        stn1 = __builtin_amdgcn_mfma_f32_16x16x32_bf16(kfr1, qf[1][1], stn1, 0, 0, 0);
      }
      short4v pf0 = packexp(stc0);
      short4v pf1 = packexp(stc1);
      rowsum[0] = __builtin_amdgcn_mfma_f32_16x16x16bf16_1k(pf0, ones, rowsum[0], 0, 0, 0);
      rowsum[1] = __builtin_amdgcn_mfma_f32_16x16x16bf16_1k(pf1, ones, rowsum[1], 0, 0, 0);
#pragma unroll
      for (int dj = 0; dj < 4; dj++) {
        short4v vfr = *(const short4v*)(Vs + (dj * 16 + l15) * 64 + voff[nj]);
        O[0][dj] = __builtin_amdgcn_mfma_f32_16x16x16bf16_1k(pf0, vfr, O[0][dj], 0, 0, 0);
        O[1][dj] = __builtin_amdgcn_mfma_f32_16x16x16bf16_1k(pf1, vfr, O[1][dj], 0, 0, 0);
      }
      stc0 = stn0;
      stc1 = stn1;
    }
  }

  // epilogue: rowsum[mi][r] holds the full key-sum for q-row quad*4+r
  const int b = bh >> 4, h = bh & 15;
#pragma unroll
  for (int mi = 0; mi < 2; mi++) {
#pragma unroll
    for (int r = 0; r < 4; r++) {
      float inv = 1.0f / rowsum[mi][r];
      int t = q0 + w * 32 + mi * 16 + quad * 4 + r;
#pragma unroll
      for (int dj = 0; dj < 4; dj++)
        AO[((size_t)(b * T_ + t)) * C_ + h * DK_ + dj * 16 + l15] = f2bf(O[mi][dj][r] * inv);
    }
  }
}

extern "C" void kernel_launch(void* const* d_in, const int* in_sizes, int n_in,
                              void* d_out, int out_size, void* d_ws, size_t ws_size,
                              hipStream_t stream) {
  const float* x    = (const float*)d_in[0];
  const float* wqkv = (const float*)d_in[1];
  const float* wo   = (const float*)d_in[2];

  char* p = (char*)d_ws;
  u16* xb    = (u16*)p; p += (size_t)M_ * C_ * 2;     // 16.8 MB
  u16* wqkvb = (u16*)p; p += (size_t)N1_ * C_ * 2;    //  6.3 MB
  u16* wob   = (u16*)p; p += (size_t)C_ * C_ * 2;     //  2.1 MB
  u16* qb    = (u16*)p; p += (size_t)M_ * C_ * 2;     // 16.8 MB  [B,H,T,64]
  u16* kb    = (u16*)p; p += (size_t)M_ * C_ * 2;     // 16.8 MB  [B,H,T,64]
  u16* vtb   = (u16*)p; p += (size_t)M_ * C_ * 2;     // 16.8 MB  tile-major swizzled
  u16* aob   = (u16*)p; p += (size_t)M_ * C_ * 2;     // 16.8 MB  [B,T,C]

  const int ncast = (M_ * C_ + N1_ * C_ + C_ * C_) / 4;
  cast_all<<<(ncast + 255) / 256, 256, 0, stream>>>(x, wqkv, wo, xb, wqkvb, wob);

  gemm_bt<0><<<dim3(N1_ / 128, M_ / 128), 256, 0, stream>>>(xb, wqkvb, qb, kb, vtb, C_, N1_);

  // grid (bh, qb): flat%8 == bh%8 -> all q-blocks of a head on one XCD
  flash_kernel<<<dim3(B_ * H_, T_ / 128), 256, 0, stream>>>(qb, kb, vtb, aob);

  gemm_bt<1><<<dim3(C_ / 128, M_ / 128), 256, 0, stream>>>(aob, wob, d_out, nullptr, nullptr, C_, C_);
}